// Round 1
// baseline (201.661 us; speedup 1.0000x reference)
//
#include <hip/hip_runtime.h>
#include <math.h>

#define N_NODES 10000
#define N_EDGES 320000
#define IN_DIM 256
#define DH 64       // D per head
#define NH 4        // heads
#define OUT_DIM 256 // D*H
#define EDIM 32
#define NT 8
#define SLOPE 0.2f

// ---------------- zero int buffer ----------------
__global__ void zero_kernel(int* p, int n) {
  int i = blockIdx.x * 256 + threadIdx.x;
  if (i < n) p[i] = 0;
}

// ---------------- he_type[t][h] = sum_d (sum_i table[t,i]*W_r[t,i,h*32+d]) * a_e[h,d]
__global__ void typed_kernel(const float* __restrict__ table,
                             const float* __restrict__ W_r,
                             const float* __restrict__ a_e,
                             float* __restrict__ he_type) {
  int tid = threadIdx.x;        // 1024 threads: t(3b) h(2b) d(5b)
  int t = tid >> 7;
  int h = (tid >> 5) & 3;
  int d = tid & 31;
  float acc = 0.f;
  for (int i = 0; i < EDIM; ++i)
    acc += table[t * EDIM + i] * W_r[(t * EDIM + i) * (EDIM * NH) + h * EDIM + d];
  acc *= a_e[h * EDIM + d];
#pragma unroll
  for (int o = 16; o; o >>= 1) acc += __shfl_xor(acc, o, 32);
  if (d == 0) he_type[t * NH + h] = acc;
}

// ---------------- fused GEMM: emb = feat@W ; res = feat@W_res + b_res ----------------
// grid (157, 8): by<4 -> W cols by*64 ; by>=4 -> W_res cols (by-4)*64
__global__ __launch_bounds__(256) void gemm_kernel(
    const float* __restrict__ feat, const float* __restrict__ W,
    const float* __restrict__ W_res, const float* __restrict__ b_res,
    float* __restrict__ emb, float* __restrict__ res) {
  __shared__ float As[32][68];  // [k][row], padded, 16B-aligned rows
  __shared__ float Bs[32][68];  // [k][col]
  const int rowbase = blockIdx.x * 64;
  const int by = blockIdx.y;
  const bool isres = by >= 4;
  const float* Wp = isres ? W_res : W;
  const int cb = (by & 3) * 64;
  const int tid = threadIdx.x;
  const int tx = tid & 15, ty = tid >> 4;
  float acc[4][4] = {};

  for (int kb = 0; kb < IN_DIM; kb += 32) {
#pragma unroll
    for (int jj = 0; jj < 2; ++jj) {
      int j = tid + jj * 256;
      // A: 64 rows x 8 float4 slots (transposed into LDS)
      int r = j >> 3;
      int ks = (j & 7) * 4;
      float4 a = make_float4(0.f, 0.f, 0.f, 0.f);
      int gr = rowbase + r;
      if (gr < N_NODES) a = *(const float4*)&feat[gr * IN_DIM + kb + ks];
      As[ks + 0][r] = a.x; As[ks + 1][r] = a.y;
      As[ks + 2][r] = a.z; As[ks + 3][r] = a.w;
      // B: 32 k x 16 float4 slots
      int k = j >> 4;
      int cs = (j & 15) * 4;
      float4 b = *(const float4*)&Wp[(kb + k) * OUT_DIM + cb + cs];
      *(float4*)&Bs[k][cs] = b;
    }
    __syncthreads();
#pragma unroll
    for (int k = 0; k < 32; ++k) {
      float4 a4 = *(const float4*)&As[k][ty * 4];
      float4 b4 = *(const float4*)&Bs[k][tx * 4];
      float av[4] = {a4.x, a4.y, a4.z, a4.w};
      float bv[4] = {b4.x, b4.y, b4.z, b4.w};
#pragma unroll
      for (int i2 = 0; i2 < 4; ++i2)
#pragma unroll
        for (int j2 = 0; j2 < 4; ++j2) acc[i2][j2] += av[i2] * bv[j2];
    }
    __syncthreads();
  }

#pragma unroll
  for (int i2 = 0; i2 < 4; ++i2) {
    int gr = rowbase + ty * 4 + i2;
    if (gr >= N_NODES) continue;
    int gc = cb + tx * 4;
    float4 o = make_float4(acc[i2][0], acc[i2][1], acc[i2][2], acc[i2][3]);
    if (!isres) {
      *(float4*)&emb[gr * OUT_DIM + gc] = o;
    } else {
      o.x += b_res[gc]; o.y += b_res[gc + 1];
      o.z += b_res[gc + 2]; o.w += b_res[gc + 3];
      *(float4*)&res[gr * OUT_DIM + gc] = o;
    }
  }
}

// ---------------- hl/hr: per-node attention dots (wave per node) ----------------
__global__ void hlhr_kernel(const float* __restrict__ emb,
                            const float* __restrict__ a_l,
                            const float* __restrict__ a_r,
                            float* __restrict__ hl, float* __restrict__ hr) {
  int n = blockIdx.x * 4 + (threadIdx.x >> 6);
  int lane = threadIdx.x & 63;
#pragma unroll
  for (int h = 0; h < NH; ++h) {
    float v = emb[n * OUT_DIM + h * DH + lane];
    float pl = v * a_l[h * DH + lane];
    float pr = v * a_r[h * DH + lane];
#pragma unroll
    for (int o = 32; o; o >>= 1) {
      pl += __shfl_xor(pl, o);
      pr += __shfl_xor(pr, o);
    }
    if (lane == 0) { hl[n * NH + h] = pl; hr[n * NH + h] = pr; }
  }
}

// ---------------- histogram of destinations ----------------
__global__ void hist_kernel(const int* __restrict__ col, int* cnt) {
  int e = blockIdx.x * 256 + threadIdx.x;
  if (e < N_EDGES) atomicAdd(&cnt[col[e]], 1);
}

// ---------------- single-block exclusive scan (N=10000) ----------------
__global__ void scan_kernel(const int* __restrict__ cnt, int* __restrict__ off,
                            int* __restrict__ cursor) {
  __shared__ int s[1024];
  int carry = 0;
  for (int chunk = 0; chunk < 10; ++chunk) {
    int i = chunk * 1024 + (int)threadIdx.x;
    int v = (i < N_NODES) ? cnt[i] : 0;
    s[threadIdx.x] = v;
    __syncthreads();
    for (int d = 1; d < 1024; d <<= 1) {
      int t = (threadIdx.x >= (unsigned)d) ? s[threadIdx.x - d] : 0;
      __syncthreads();
      s[threadIdx.x] += t;
      __syncthreads();
    }
    if (i < N_NODES) {
      int ex = carry + s[threadIdx.x] - v;
      off[i] = ex;
      cursor[i] = ex;
    }
    carry += s[1023];
    __syncthreads();
  }
  if (threadIdx.x == 0) off[N_NODES] = carry;
}

// ---------------- scatter edge ids into CSR ----------------
__global__ void scatter_kernel(const int* __restrict__ col, int* cursor,
                               int* __restrict__ eidx) {
  int e = blockIdx.x * 256 + threadIdx.x;
  if (e < N_EDGES) {
    int p = atomicAdd(&cursor[col[e]], 1);
    eidx[p] = e;
  }
}

// ---------------- per-edge attention ----------------
__global__ void att_kernel(const int* __restrict__ row, const int* __restrict__ col,
                           const int* __restrict__ et, const float* __restrict__ ew,
                           const float* __restrict__ hl, const float* __restrict__ hr,
                           const float* __restrict__ he_type, float* __restrict__ att) {
  int e = blockIdx.x * 256 + threadIdx.x;
  if (e >= N_EDGES) return;
  int r = row[e], c = col[e], t = et[e];
  float w = ew[e];
  float4 L = *(const float4*)&hl[r * 4];
  float4 R = *(const float4*)&hr[c * 4];
  float4 Hh = *(const float4*)&he_type[t * 4];
  float x[4] = {L.x + R.x + Hh.x, L.y + R.y + Hh.y, L.z + R.z + Hh.z, L.w + R.w + Hh.w};
  float4 o;
  float* op = &o.x;
#pragma unroll
  for (int h = 0; h < 4; ++h) {
    float v = x[h];
    v = v >= 0.f ? v : SLOPE * v;
    op[h] = w / (1.f + expf(-v));
  }
  *(float4*)&att[e * 4] = o;
}

// ---------------- aggregation: wave per destination node, fused transpose+residual+ELU
__global__ __launch_bounds__(256) void agg_kernel(
    const int* __restrict__ off, const int* __restrict__ eidx,
    const int* __restrict__ row, const float* __restrict__ att,
    const float* __restrict__ emb, const float* __restrict__ res,
    float* __restrict__ out) {
  int n = blockIdx.x * 4 + (threadIdx.x >> 6);
  int lane = threadIdx.x & 63;
  float acc0 = 0.f, acc1 = 0.f, acc2 = 0.f, acc3 = 0.f;
  int s = off[n], e = off[n + 1];
  for (int i = s; i < e; ++i) {
    int eid = eidx[i];
    int src = row[eid];
    float4 a = *(const float4*)&att[eid * 4];
    const float* eb = emb + src * OUT_DIM;
    acc0 = fmaf(eb[0 * DH + lane], a.x, acc0);
    acc1 = fmaf(eb[1 * DH + lane], a.y, acc1);
    acc2 = fmaf(eb[2 * DH + lane], a.z, acc2);
    acc3 = fmaf(eb[3 * DH + lane], a.w, acc3);
  }
  // out[n][d*H + h], d = lane -> out[n*256 + lane*4 + h]
  float4 r4 = *(const float4*)&res[n * OUT_DIM + lane * 4];
  float v0 = acc0 + r4.x, v1 = acc1 + r4.y, v2 = acc2 + r4.z, v3 = acc3 + r4.w;
  float4 o;
  o.x = v0 > 0.f ? v0 : expm1f(v0);
  o.y = v1 > 0.f ? v1 : expm1f(v1);
  o.z = v2 > 0.f ? v2 : expm1f(v2);
  o.w = v3 > 0.f ? v3 : expm1f(v3);
  *(float4*)&out[n * OUT_DIM + lane * 4] = o;
}

extern "C" void kernel_launch(void* const* d_in, const int* in_sizes, int n_in,
                              void* d_out, int out_size, void* d_ws, size_t ws_size,
                              hipStream_t stream) {
  const float* feat = (const float*)d_in[0];
  const float* edge_weight = (const float*)d_in[1];
  const int* row = (const int*)d_in[2];
  const int* col = (const int*)d_in[3];
  const int* etype = (const int*)d_in[4];
  const float* W = (const float*)d_in[5];
  const float* edge_emb_table = (const float*)d_in[6];
  const float* W_r = (const float*)d_in[7];
  const float* a_l = (const float*)d_in[8];
  const float* a_r = (const float*)d_in[9];
  const float* a_e = (const float*)d_in[10];
  const float* W_res = (const float*)d_in[11];
  const float* b_res = (const float*)d_in[12];
  float* out = (float*)d_out;

  // workspace carve-up (256B aligned chunks)
  char* w = (char*)d_ws;
  auto alloc = [&](size_t bytes) {
    char* p = w;
    w += (bytes + 255) & ~(size_t)255;
    return p;
  };
  float* emb = (float*)alloc((size_t)N_NODES * OUT_DIM * 4);
  float* res = (float*)alloc((size_t)N_NODES * OUT_DIM * 4);
  float* att = (float*)alloc((size_t)N_EDGES * NH * 4);
  float* hl = (float*)alloc((size_t)N_NODES * NH * 4);
  float* hr = (float*)alloc((size_t)N_NODES * NH * 4);
  float* he_type = (float*)alloc(NT * NH * 4);
  int* cnt = (int*)alloc((size_t)(N_NODES + 1) * 4);
  int* off = (int*)alloc((size_t)(N_NODES + 1) * 4);
  int* cursor = (int*)alloc((size_t)N_NODES * 4);
  int* eidx = (int*)alloc((size_t)N_EDGES * 4);

  zero_kernel<<<(N_NODES + 1 + 255) / 256, 256, 0, stream>>>(cnt, N_NODES + 1);
  typed_kernel<<<1, 1024, 0, stream>>>(edge_emb_table, W_r, a_e, he_type);
  gemm_kernel<<<dim3((N_NODES + 63) / 64, 8), 256, 0, stream>>>(feat, W, W_res, b_res,
                                                                emb, res);
  hlhr_kernel<<<N_NODES / 4, 256, 0, stream>>>(emb, a_l, a_r, hl, hr);
  hist_kernel<<<(N_EDGES + 255) / 256, 256, 0, stream>>>(col, cnt);
  scan_kernel<<<1, 1024, 0, stream>>>(cnt, off, cursor);
  scatter_kernel<<<(N_EDGES + 255) / 256, 256, 0, stream>>>(col, cursor, eidx);
  att_kernel<<<(N_EDGES + 255) / 256, 256, 0, stream>>>(row, col, etype, edge_weight,
                                                        hl, hr, he_type, att);
  agg_kernel<<<N_NODES / 4, 256, 0, stream>>>(off, eidx, row, att, emb, res, out);
}

// Round 2
// 144.181 us; speedup vs baseline: 1.3987x; 1.3987x over previous
//
#include <hip/hip_runtime.h>
#include <hip/hip_bf16.h>
#include <math.h>

#define N_NODES 10000
#define MPAD 10112        // 79 * 128
#define N_EDGES 320000
#define IN_DIM 256
#define DH 64
#define NH 4
#define OUT_DIM 256
#define EDIM 32
#define NT 8
#define SLOPE 0.2f

typedef __attribute__((ext_vector_type(8))) short short8b;
typedef __attribute__((ext_vector_type(4))) float f32x4;

__device__ __forceinline__ float bf2f(ushort u) {
  return __uint_as_float(((unsigned)u) << 16);
}
__device__ __forceinline__ ushort f2bf(float f) {
  __hip_bfloat16 h = __float2bfloat16(f);
  return *(ushort*)&h;
}

// ---------------- convert: featb (bf16, padded rows zeroed) + Wtb (bf16, [col][k] of W||W_res)
__global__ void convert_kernel(const float* __restrict__ feat,
                               const float* __restrict__ W,
                               const float* __restrict__ W_res,
                               ushort* __restrict__ featb,
                               ushort* __restrict__ Wtb) {
  const int FG = (MPAD * IN_DIM) / 8;
  int i = blockIdx.x * 256 + threadIdx.x;
  if (i < FG) {
    int idx = i * 8;
    int r = idx >> 8;
    int4 o = make_int4(0, 0, 0, 0);
    ushort* tp = (ushort*)&o;
    if (r < N_NODES) {
      float4 x = *(const float4*)&feat[idx];
      float4 y = *(const float4*)&feat[idx + 4];
      tp[0] = f2bf(x.x); tp[1] = f2bf(x.y); tp[2] = f2bf(x.z); tp[3] = f2bf(x.w);
      tp[4] = f2bf(y.x); tp[5] = f2bf(y.y); tp[6] = f2bf(y.z); tp[7] = f2bf(y.w);
    }
    *(int4*)&featb[idx] = o;
  } else if (i < FG + 512 * 256) {
    int j = i - FG;
    int c = j >> 8, k = j & 255;
    float v = (c < 256) ? W[k * 256 + c] : W_res[k * 256 + (c - 256)];
    Wtb[c * 256 + k] = f2bf(v);
  }
}

// ---------------- he_type[t][h] ----------------
__global__ void typed_kernel(const float* __restrict__ table,
                             const float* __restrict__ W_r,
                             const float* __restrict__ a_e,
                             float* __restrict__ he_type) {
  int tid = threadIdx.x;
  int t = tid >> 7;
  int h = (tid >> 5) & 3;
  int d = tid & 31;
  float acc = 0.f;
  for (int i = 0; i < EDIM; ++i)
    acc += table[t * EDIM + i] * W_r[(t * EDIM + i) * (EDIM * NH) + h * EDIM + d];
  acc *= a_e[h * EDIM + d];
#pragma unroll
  for (int o = 16; o; o >>= 1) acc += __shfl_xor(acc, o, 32);
  if (d == 0) he_type[t * NH + h] = acc;
}

// ---------------- MFMA GEMM: C[M,512] = featb @ Wtb^T ; cols<256 -> emb_t (bf16, [n][d*4+h]),
// cols>=256 -> res (fp32) + b_res. Direct-from-global, no LDS, 2 waves/block, 128x64 per block.
__global__ __launch_bounds__(128) void mfma_gemm_kernel(
    const ushort* __restrict__ featb, const ushort* __restrict__ Wtb,
    const float* __restrict__ b_res, ushort* __restrict__ emb_t,
    float* __restrict__ res) {
  const int wave = threadIdx.x >> 6, lane = threadIdx.x & 63;
  const int row0 = blockIdx.x * 128 + wave * 64;
  const int col0 = blockIdx.y * 64;
  const int lr = lane & 15;
  const int lk = (lane >> 4) * 8;
  f32x4 acc[4][4] = {};
  const ushort* Ab = featb + (size_t)(row0 + lr) * IN_DIM + lk;
  const ushort* Bb = Wtb + (size_t)(col0 + lr) * IN_DIM + lk;

#pragma unroll
  for (int ks = 0; ks < 8; ++ks) {
    short8b a[4], b[4];
#pragma unroll
    for (int m = 0; m < 4; ++m)
      a[m] = *(const short8b*)(Ab + (size_t)(m * 16) * IN_DIM + ks * 32);
#pragma unroll
    for (int n = 0; n < 4; ++n)
      b[n] = *(const short8b*)(Bb + (size_t)(n * 16) * IN_DIM + ks * 32);
#pragma unroll
    for (int m = 0; m < 4; ++m)
#pragma unroll
      for (int n = 0; n < 4; ++n)
        acc[m][n] = __builtin_amdgcn_mfma_f32_16x16x32_bf16(a[m], b[n], acc[m][n], 0, 0, 0);
  }

  const int rbase = row0 + (lane >> 4) * 4;
  if (col0 < 256) {
#pragma unroll
    for (int m = 0; m < 4; ++m)
#pragma unroll
      for (int n = 0; n < 4; ++n) {
        int c = col0 + n * 16 + lr;
        int d = c & 63, h = c >> 6;
#pragma unroll
        for (int j = 0; j < 4; ++j) {
          int r = rbase + m * 16 + j;
          if (r < N_NODES) emb_t[(size_t)r * 256 + d * 4 + h] = f2bf(acc[m][n][j]);
        }
      }
  } else {
#pragma unroll
    for (int m = 0; m < 4; ++m)
#pragma unroll
      for (int n = 0; n < 4; ++n) {
        int c = (col0 - 256) + n * 16 + lr;
        float br = b_res[c];
#pragma unroll
        for (int j = 0; j < 4; ++j) {
          int r = rbase + m * 16 + j;
          if (r < N_NODES) res[(size_t)r * 256 + c] = acc[m][n][j] + br;
        }
      }
  }
}

// ---------------- hl/hr from emb_t (wave per node) ----------------
__global__ void hlhr_kernel(const ushort* __restrict__ emb_t,
                            const float* __restrict__ a_l,
                            const float* __restrict__ a_r,
                            float* __restrict__ hl, float* __restrict__ hr) {
  int n = blockIdx.x * 4 + (threadIdx.x >> 6);
  int lane = threadIdx.x & 63;
  ushort4 v = *(const ushort4*)&emb_t[(size_t)n * 256 + lane * 4];
  float vf[4] = {bf2f(v.x), bf2f(v.y), bf2f(v.z), bf2f(v.w)};
  float pl[4], pr[4];
#pragma unroll
  for (int h = 0; h < 4; ++h) {
    pl[h] = vf[h] * a_l[h * DH + lane];
    pr[h] = vf[h] * a_r[h * DH + lane];
  }
#pragma unroll
  for (int o = 32; o; o >>= 1) {
#pragma unroll
    for (int h = 0; h < 4; ++h) {
      pl[h] += __shfl_xor(pl[h], o);
      pr[h] += __shfl_xor(pr[h], o);
    }
  }
  if (lane == 0) {
    *(float4*)&hl[n * 4] = make_float4(pl[0], pl[1], pl[2], pl[3]);
    *(float4*)&hr[n * 4] = make_float4(pr[0], pr[1], pr[2], pr[3]);
  }
}

// ---------------- histogram of destinations ----------------
__global__ void hist_kernel(const int* __restrict__ col, int* cnt) {
  int e = blockIdx.x * 256 + threadIdx.x;
  if (e < N_EDGES) atomicAdd(&cnt[col[e]], 1);
}

// ---------------- single-block exclusive scan, shfl-based ----------------
__global__ void scan_kernel(const int* __restrict__ cnt, int* __restrict__ off,
                            int* __restrict__ cursor) {
  __shared__ int wsum[16];
  int tid = threadIdx.x, wid = tid >> 6, lane = tid & 63;
  int carry = 0;
  for (int chunk = 0; chunk < 10; ++chunk) {
    int i = chunk * 1024 + tid;
    int v = (i < N_NODES) ? cnt[i] : 0;
    int x = v;
#pragma unroll
    for (int d = 1; d < 64; d <<= 1) {
      int t = __shfl_up(x, d);
      if (lane >= d) x += t;
    }
    if (lane == 63) wsum[wid] = x;
    __syncthreads();
    if (wid == 0 && lane < 16) {
      int w = wsum[lane];
#pragma unroll
      for (int d = 1; d < 16; d <<= 1) {
        int t = __shfl_up(w, d);
        if (lane >= d) w += t;
      }
      wsum[lane] = w;
    }
    __syncthreads();
    int base = carry + (wid ? wsum[wid - 1] : 0);
    int total = wsum[15];
    if (i < N_NODES) {
      int ex = base + x - v;
      off[i] = ex;
      cursor[i] = ex;
    }
    carry += total;
    __syncthreads();
  }
  if (tid == 0) off[N_NODES] = carry;
}

// ---------------- scatter edge ids into CSR ----------------
__global__ void scatter_kernel(const int* __restrict__ col, int* cursor,
                               int* __restrict__ eidx) {
  int e = blockIdx.x * 256 + threadIdx.x;
  if (e < N_EDGES) {
    int p = atomicAdd(&cursor[col[e]], 1);
    eidx[p] = e;
  }
}

// ---------------- per-edge attention ----------------
__global__ void att_kernel(const int* __restrict__ row, const int* __restrict__ col,
                           const int* __restrict__ et, const float* __restrict__ ew,
                           const float* __restrict__ hl, const float* __restrict__ hr,
                           const float* __restrict__ he_type, float* __restrict__ att) {
  int e = blockIdx.x * 256 + threadIdx.x;
  if (e >= N_EDGES) return;
  int r = row[e], c = col[e], t = et[e];
  float w = ew[e];
  float4 L = *(const float4*)&hl[r * 4];
  float4 R = *(const float4*)&hr[c * 4];
  float4 Hh = *(const float4*)&he_type[t * 4];
  float x[4] = {L.x + R.x + Hh.x, L.y + R.y + Hh.y, L.z + R.z + Hh.z, L.w + R.w + Hh.w};
  float4 o;
  float* op = &o.x;
#pragma unroll
  for (int h = 0; h < 4; ++h) {
    float v = x[h];
    v = v >= 0.f ? v : SLOPE * v;
    op[h] = w / (1.f + expf(-v));
  }
  *(float4*)&att[e * 4] = o;
}

// ---------------- aggregation: wave per dst node, batched metadata + bf16 gather
__global__ __launch_bounds__(256) void agg_kernel(
    const int* __restrict__ off, const int* __restrict__ eidx,
    const int* __restrict__ row, const float* __restrict__ att,
    const ushort* __restrict__ emb_t, const float* __restrict__ res,
    float* __restrict__ out) {
  int n = blockIdx.x * 4 + (threadIdx.x >> 6);
  int lane = threadIdx.x & 63;
  float acc0 = 0.f, acc1 = 0.f, acc2 = 0.f, acc3 = 0.f;
  int s = off[n], e = off[n + 1];
  for (int base = s; base < e; base += 64) {
    int cnt = min(64, e - base);
    int src = 0;
    float ax = 0.f, ay = 0.f, az = 0.f, aw = 0.f;
    if (lane < cnt) {
      int eid = eidx[base + lane];
      src = row[eid];
      float4 a = *(const float4*)&att[eid * 4];
      ax = a.x; ay = a.y; az = a.z; aw = a.w;
    }
#pragma unroll 4
    for (int j = 0; j < cnt; ++j) {
      int sj = __shfl(src, j);
      float bx = __shfl(ax, j), by = __shfl(ay, j);
      float bz = __shfl(az, j), bw = __shfl(aw, j);
      ushort4 v = *(const ushort4*)&emb_t[(size_t)sj * 256 + lane * 4];
      acc0 = fmaf(bf2f(v.x), bx, acc0);
      acc1 = fmaf(bf2f(v.y), by, acc1);
      acc2 = fmaf(bf2f(v.z), bz, acc2);
      acc3 = fmaf(bf2f(v.w), bw, acc3);
    }
  }
  // out[n][d*4+h], d = lane
  float4 r4 = *(const float4*)&res[(size_t)n * 256 + lane * 4];
  float v0 = acc0 + r4.x, v1 = acc1 + r4.y, v2 = acc2 + r4.z, v3 = acc3 + r4.w;
  float4 o;
  o.x = v0 > 0.f ? v0 : expm1f(v0);
  o.y = v1 > 0.f ? v1 : expm1f(v1);
  o.z = v2 > 0.f ? v2 : expm1f(v2);
  o.w = v3 > 0.f ? v3 : expm1f(v3);
  *(float4*)&out[(size_t)n * 256 + lane * 4] = o;
}

extern "C" void kernel_launch(void* const* d_in, const int* in_sizes, int n_in,
                              void* d_out, int out_size, void* d_ws, size_t ws_size,
                              hipStream_t stream) {
  const float* feat = (const float*)d_in[0];
  const float* edge_weight = (const float*)d_in[1];
  const int* row = (const int*)d_in[2];
  const int* col = (const int*)d_in[3];
  const int* etype = (const int*)d_in[4];
  const float* W = (const float*)d_in[5];
  const float* edge_emb_table = (const float*)d_in[6];
  const float* W_r = (const float*)d_in[7];
  const float* a_l = (const float*)d_in[8];
  const float* a_r = (const float*)d_in[9];
  const float* a_e = (const float*)d_in[10];
  const float* W_res = (const float*)d_in[11];
  const float* b_res = (const float*)d_in[12];
  float* out = (float*)d_out;

  char* w = (char*)d_ws;
  auto alloc = [&](size_t bytes) {
    char* p = w;
    w += (bytes + 255) & ~(size_t)255;
    return p;
  };
  ushort* featb = (ushort*)alloc((size_t)MPAD * IN_DIM * 2);
  ushort* Wtb = (ushort*)alloc((size_t)512 * 256 * 2);
  ushort* emb_t = (ushort*)alloc((size_t)N_NODES * 256 * 2);
  float* res = (float*)alloc((size_t)N_NODES * 256 * 4);
  float* att = (float*)alloc((size_t)N_EDGES * NH * 4);
  float* hl = (float*)alloc((size_t)N_NODES * NH * 4);
  float* hr = (float*)alloc((size_t)N_NODES * NH * 4);
  float* he_type = (float*)alloc(NT * NH * 4);
  int* cnt = (int*)alloc((size_t)(N_NODES + 1) * 4);
  int* off = (int*)alloc((size_t)(N_NODES + 1) * 4);
  int* cursor = (int*)alloc((size_t)N_NODES * 4);
  int* eidx = (int*)alloc((size_t)N_EDGES * 4);

  hipMemsetAsync(cnt, 0, (size_t)(N_NODES + 1) * 4, stream);

  const int FG = (MPAD * IN_DIM) / 8;
  convert_kernel<<<(FG + 512 * 256 + 255) / 256, 256, 0, stream>>>(feat, W, W_res,
                                                                   featb, Wtb);
  typed_kernel<<<1, 1024, 0, stream>>>(edge_emb_table, W_r, a_e, he_type);
  mfma_gemm_kernel<<<dim3(MPAD / 128, 8), 128, 0, stream>>>(featb, Wtb, b_res,
                                                            emb_t, res);
  hlhr_kernel<<<N_NODES / 4, 256, 0, stream>>>(emb_t, a_l, a_r, hl, hr);
  hist_kernel<<<(N_EDGES + 255) / 256, 256, 0, stream>>>(col, cnt);
  scan_kernel<<<1, 1024, 0, stream>>>(cnt, off, cursor);
  scatter_kernel<<<(N_EDGES + 255) / 256, 256, 0, stream>>>(col, cursor, eidx);
  att_kernel<<<(N_EDGES + 255) / 256, 256, 0, stream>>>(row, col, etype, edge_weight,
                                                        hl, hr, he_type, att);
  agg_kernel<<<N_NODES / 4, 256, 0, stream>>>(off, eidx, row, att, emb_t, res, out);
}

// Round 3
// 123.528 us; speedup vs baseline: 1.6325x; 1.1672x over previous
//
#include <hip/hip_runtime.h>
#include <hip/hip_bf16.h>
#include <math.h>

#define N_NODES 10000
#define MPAD 10112        // 79 * 128
#define N_EDGES 320000
#define IN_DIM 256
#define DH 64
#define NH 4
#define OUT_DIM 256
#define EDIM 32
#define NT 8
#define SLOPE 0.2f

// prep kernel block ranges
#define FB_BLOCKS 1264    // featb: 1264*256 threads * 8 bf16 = 10112*256
#define WT_BLOCKS 512     // Wtb: 512*256 = 512 cols * 256 k
#define HIST_BLOCKS 1250  // 1250*256 = 320000 edges
#define TYPED_BLOCKS 4    // 1024 threads

typedef __attribute__((ext_vector_type(8))) short short8b;
typedef __attribute__((ext_vector_type(4))) float f32x4;

__device__ __forceinline__ float bf2f(ushort u) {
  return __uint_as_float(((unsigned)u) << 16);
}
__device__ __forceinline__ ushort f2bf(float f) {
  __hip_bfloat16 h = __float2bfloat16(f);
  return *(ushort*)&h;
}

// ---------------- fused prep: featb + Wtb + histogram + he_type ----------------
__global__ void prep_kernel(const float* __restrict__ feat,
                            const float* __restrict__ W,
                            const float* __restrict__ W_res,
                            const int* __restrict__ col,
                            const float* __restrict__ table,
                            const float* __restrict__ W_r,
                            const float* __restrict__ a_e,
                            ushort* __restrict__ featb,
                            ushort* __restrict__ Wtb,
                            int* __restrict__ cnt,
                            float* __restrict__ he_type) {
  int b = blockIdx.x;
  if (b < FB_BLOCKS) {
    int i = b * 256 + threadIdx.x;   // each writes 8 bf16 (16B)
    int idx = i * 8;
    int r = idx >> 8;
    int4 o = make_int4(0, 0, 0, 0);
    ushort* tp = (ushort*)&o;
    if (r < N_NODES) {
      float4 x = *(const float4*)&feat[idx];
      float4 y = *(const float4*)&feat[idx + 4];
      tp[0] = f2bf(x.x); tp[1] = f2bf(x.y); tp[2] = f2bf(x.z); tp[3] = f2bf(x.w);
      tp[4] = f2bf(y.x); tp[5] = f2bf(y.y); tp[6] = f2bf(y.z); tp[7] = f2bf(y.w);
    }
    *(int4*)&featb[idx] = o;
  } else if (b < FB_BLOCKS + WT_BLOCKS) {
    int j = (b - FB_BLOCKS) * 256 + threadIdx.x;
    int c = j >> 8, k = j & 255;
    float v = (c < 256) ? W[k * 256 + c] : W_res[k * 256 + (c - 256)];
    Wtb[c * 256 + k] = f2bf(v);
  } else if (b < FB_BLOCKS + WT_BLOCKS + HIST_BLOCKS) {
    int e = (b - FB_BLOCKS - WT_BLOCKS) * 256 + threadIdx.x;
    atomicAdd(&cnt[col[e]], 1);
  } else {
    int tid = (b - FB_BLOCKS - WT_BLOCKS - HIST_BLOCKS) * 256 + threadIdx.x; // 0..1023
    int t = tid >> 7;
    int h = (tid >> 5) & 3;
    int d = tid & 31;
    float acc = 0.f;
    for (int i = 0; i < EDIM; ++i)
      acc += table[t * EDIM + i] * W_r[(t * EDIM + i) * (EDIM * NH) + h * EDIM + d];
    acc *= a_e[h * EDIM + d];
#pragma unroll
    for (int o = 16; o; o >>= 1) acc += __shfl_xor(acc, o, 32);
    if (d == 0) he_type[t * NH + h] = acc;
  }
}

// ---------------- MFMA GEMM + fused hl/hr epilogue ----------------
// C[M,512] = featb @ Wtb^T ; cols<256 -> emb_t (bf16, [n][d*4+h]) + hl/hr,
// cols>=256 -> res (fp32) + b_res. 2 waves/block, 128x64 per block.
__global__ __launch_bounds__(128) void mfma_gemm_kernel(
    const ushort* __restrict__ featb, const ushort* __restrict__ Wtb,
    const float* __restrict__ b_res,
    const float* __restrict__ a_l, const float* __restrict__ a_r,
    ushort* __restrict__ emb_t, float* __restrict__ res,
    float* __restrict__ hl, float* __restrict__ hr) {
  const int wave = threadIdx.x >> 6, lane = threadIdx.x & 63;
  const int row0 = blockIdx.x * 128 + wave * 64;
  const int col0 = blockIdx.y * 64;
  const int lr = lane & 15;
  const int lk = (lane >> 4) * 8;
  f32x4 acc[4][4] = {};
  const ushort* Ab = featb + (size_t)(row0 + lr) * IN_DIM + lk;
  const ushort* Bb = Wtb + (size_t)(col0 + lr) * IN_DIM + lk;

#pragma unroll
  for (int ks = 0; ks < 8; ++ks) {
    short8b a[4], b[4];
#pragma unroll
    for (int m = 0; m < 4; ++m)
      a[m] = *(const short8b*)(Ab + (size_t)(m * 16) * IN_DIM + ks * 32);
#pragma unroll
    for (int n = 0; n < 4; ++n)
      b[n] = *(const short8b*)(Bb + (size_t)(n * 16) * IN_DIM + ks * 32);
#pragma unroll
    for (int m = 0; m < 4; ++m)
#pragma unroll
      for (int n = 0; n < 4; ++n)
        acc[m][n] = __builtin_amdgcn_mfma_f32_16x16x32_bf16(a[m], b[n], acc[m][n], 0, 0, 0);
  }

  const int rbase = row0 + (lane >> 4) * 4;
  if (col0 < 256) {
    // emb_t writes: [n][d*4+h]
#pragma unroll
    for (int m = 0; m < 4; ++m)
#pragma unroll
      for (int n = 0; n < 4; ++n) {
        int c = col0 + n * 16 + lr;
        int d = c & 63, h = c >> 6;
#pragma unroll
        for (int j = 0; j < 4; ++j) {
          int r = rbase + m * 16 + j;
          if (r < N_NODES) emb_t[(size_t)r * 256 + d * 4 + h] = f2bf(acc[m][n][j]);
        }
      }
    // hl/hr: this block covers exactly head h = col0>>6, all 64 d values
    const int h = col0 >> 6;
    float al[4], ar[4];
#pragma unroll
    for (int n = 0; n < 4; ++n) {
      al[n] = a_l[h * 64 + n * 16 + lr];
      ar[n] = a_r[h * 64 + n * 16 + lr];
    }
#pragma unroll
    for (int m = 0; m < 4; ++m)
#pragma unroll
      for (int j = 0; j < 4; ++j) {
        float pl = acc[m][0][j] * al[0] + acc[m][1][j] * al[1] +
                   acc[m][2][j] * al[2] + acc[m][3][j] * al[3];
        float pr = acc[m][0][j] * ar[0] + acc[m][1][j] * ar[1] +
                   acc[m][2][j] * ar[2] + acc[m][3][j] * ar[3];
#pragma unroll
        for (int o = 1; o < 16; o <<= 1) {
          pl += __shfl_xor(pl, o);
          pr += __shfl_xor(pr, o);
        }
        int r = rbase + m * 16 + j;
        if (lr == 0 && r < N_NODES) {
          hl[r * 4 + h] = pl;
          hr[r * 4 + h] = pr;
        }
      }
  } else {
#pragma unroll
    for (int m = 0; m < 4; ++m)
#pragma unroll
      for (int n = 0; n < 4; ++n) {
        int c = (col0 - 256) + n * 16 + lr;
        float br = b_res[c];
#pragma unroll
        for (int j = 0; j < 4; ++j) {
          int r = rbase + m * 16 + j;
          if (r < N_NODES) res[(size_t)r * 256 + c] = acc[m][n][j] + br;
        }
      }
  }
}

// ---------------- single-block exclusive scan, shfl-based ----------------
__global__ void scan_kernel(const int* __restrict__ cnt, int* __restrict__ off,
                            int* __restrict__ cursor) {
  __shared__ int wsum[16];
  int tid = threadIdx.x, wid = tid >> 6, lane = tid & 63;
  int carry = 0;
  for (int chunk = 0; chunk < 10; ++chunk) {
    int i = chunk * 1024 + tid;
    int v = (i < N_NODES) ? cnt[i] : 0;
    int x = v;
#pragma unroll
    for (int d = 1; d < 64; d <<= 1) {
      int t = __shfl_up(x, d);
      if (lane >= d) x += t;
    }
    if (lane == 63) wsum[wid] = x;
    __syncthreads();
    if (wid == 0 && lane < 16) {
      int w = wsum[lane];
#pragma unroll
      for (int d = 1; d < 16; d <<= 1) {
        int t = __shfl_up(w, d);
        if (lane >= d) w += t;
      }
      wsum[lane] = w;
    }
    __syncthreads();
    int base = carry + (wid ? wsum[wid - 1] : 0);
    int total = wsum[15];
    if (i < N_NODES) {
      int ex = base + x - v;
      off[i] = ex;
      cursor[i] = ex;
    }
    carry += total;
    __syncthreads();
  }
  if (tid == 0) off[N_NODES] = carry;
}

// ---------------- fused scatter + attention: write att/src in CSR order ----------------
__global__ void scatter_att_kernel(const int* __restrict__ row,
                                   const int* __restrict__ colv,
                                   const int* __restrict__ et,
                                   const float* __restrict__ ew,
                                   const float* __restrict__ hl,
                                   const float* __restrict__ hr,
                                   const float* __restrict__ he_type,
                                   int* cursor, int* __restrict__ srcp,
                                   float* __restrict__ attp) {
  int e = blockIdx.x * 256 + threadIdx.x;
  if (e >= N_EDGES) return;
  int r = row[e], c = colv[e], t = et[e];
  float w = ew[e];
  float4 L = *(const float4*)&hl[r * 4];
  float4 R = *(const float4*)&hr[c * 4];
  float4 Hh = *(const float4*)&he_type[t * 4];
  float x[4] = {L.x + R.x + Hh.x, L.y + R.y + Hh.y, L.z + R.z + Hh.z, L.w + R.w + Hh.w};
  float4 o;
  float* op = &o.x;
#pragma unroll
  for (int h = 0; h < 4; ++h) {
    float v = x[h];
    v = v >= 0.f ? v : SLOPE * v;
    op[h] = w / (1.f + expf(-v));
  }
  int p = atomicAdd(&cursor[c], 1);
  srcp[p] = r;
  *(float4*)&attp[(size_t)p * 4] = o;
}

// ---------------- aggregation: wave per dst node, coalesced metadata + bf16 gather
__global__ __launch_bounds__(256) void agg_kernel(
    const int* __restrict__ off, const int* __restrict__ srcp,
    const float* __restrict__ attp,
    const ushort* __restrict__ emb_t, const float* __restrict__ res,
    float* __restrict__ out) {
  int n = blockIdx.x * 4 + (threadIdx.x >> 6);
  int lane = threadIdx.x & 63;
  float acc0 = 0.f, acc1 = 0.f, acc2 = 0.f, acc3 = 0.f;
  int s = off[n], e = off[n + 1];
  for (int base = s; base < e; base += 64) {
    int cnt = min(64, e - base);
    int src = 0;
    float ax = 0.f, ay = 0.f, az = 0.f, aw = 0.f;
    if (lane < cnt) {
      src = srcp[base + lane];
      float4 a = *(const float4*)&attp[(size_t)(base + lane) * 4];
      ax = a.x; ay = a.y; az = a.z; aw = a.w;
    }
#pragma unroll 4
    for (int j = 0; j < cnt; ++j) {
      int sj = __shfl(src, j);
      float bx = __shfl(ax, j), by = __shfl(ay, j);
      float bz = __shfl(az, j), bw = __shfl(aw, j);
      ushort4 v = *(const ushort4*)&emb_t[(size_t)sj * 256 + lane * 4];
      acc0 = fmaf(bf2f(v.x), bx, acc0);
      acc1 = fmaf(bf2f(v.y), by, acc1);
      acc2 = fmaf(bf2f(v.z), bz, acc2);
      acc3 = fmaf(bf2f(v.w), bw, acc3);
    }
  }
  float4 r4 = *(const float4*)&res[(size_t)n * 256 + lane * 4];
  float v0 = acc0 + r4.x, v1 = acc1 + r4.y, v2 = acc2 + r4.z, v3 = acc3 + r4.w;
  float4 o;
  o.x = v0 > 0.f ? v0 : expm1f(v0);
  o.y = v1 > 0.f ? v1 : expm1f(v1);
  o.z = v2 > 0.f ? v2 : expm1f(v2);
  o.w = v3 > 0.f ? v3 : expm1f(v3);
  *(float4*)&out[(size_t)n * 256 + lane * 4] = o;
}

extern "C" void kernel_launch(void* const* d_in, const int* in_sizes, int n_in,
                              void* d_out, int out_size, void* d_ws, size_t ws_size,
                              hipStream_t stream) {
  const float* feat = (const float*)d_in[0];
  const float* edge_weight = (const float*)d_in[1];
  const int* row = (const int*)d_in[2];
  const int* col = (const int*)d_in[3];
  const int* etype = (const int*)d_in[4];
  const float* W = (const float*)d_in[5];
  const float* edge_emb_table = (const float*)d_in[6];
  const float* W_r = (const float*)d_in[7];
  const float* a_l = (const float*)d_in[8];
  const float* a_r = (const float*)d_in[9];
  const float* a_e = (const float*)d_in[10];
  const float* W_res = (const float*)d_in[11];
  const float* b_res = (const float*)d_in[12];
  float* out = (float*)d_out;

  char* w = (char*)d_ws;
  auto alloc = [&](size_t bytes) {
    char* p = w;
    w += (bytes + 255) & ~(size_t)255;
    return p;
  };
  ushort* featb = (ushort*)alloc((size_t)MPAD * IN_DIM * 2);
  ushort* Wtb = (ushort*)alloc((size_t)512 * 256 * 2);
  ushort* emb_t = (ushort*)alloc((size_t)N_NODES * 256 * 2);
  float* res = (float*)alloc((size_t)N_NODES * 256 * 4);
  float* attp = (float*)alloc((size_t)N_EDGES * NH * 4);
  int* srcp = (int*)alloc((size_t)N_EDGES * 4);
  float* hl = (float*)alloc((size_t)N_NODES * NH * 4);
  float* hr = (float*)alloc((size_t)N_NODES * NH * 4);
  float* he_type = (float*)alloc(NT * NH * 4);
  int* cnt = (int*)alloc((size_t)(N_NODES + 1) * 4);
  int* off = (int*)alloc((size_t)(N_NODES + 1) * 4);
  int* cursor = (int*)alloc((size_t)N_NODES * 4);

  hipMemsetAsync(cnt, 0, (size_t)(N_NODES + 1) * 4, stream);

  const int PREP_BLOCKS = FB_BLOCKS + WT_BLOCKS + HIST_BLOCKS + TYPED_BLOCKS;
  prep_kernel<<<PREP_BLOCKS, 256, 0, stream>>>(feat, W, W_res, col,
                                               edge_emb_table, W_r, a_e,
                                               featb, Wtb, cnt, he_type);
  mfma_gemm_kernel<<<dim3(MPAD / 128, 8), 128, 0, stream>>>(featb, Wtb, b_res,
                                                            a_l, a_r, emb_t, res,
                                                            hl, hr);
  scan_kernel<<<1, 1024, 0, stream>>>(cnt, off, cursor);
  scatter_att_kernel<<<(N_EDGES + 255) / 256, 256, 0, stream>>>(
      row, col, etype, edge_weight, hl, hr, he_type, cursor, srcp, attp);
  agg_kernel<<<N_NODES / 4, 256, 0, stream>>>(off, srcp, attp, emb_t, res, out);
}